// Round 10
// baseline (160.807 us; speedup 1.0000x reference)
//
#include <hip/hip_runtime.h>
#include <hip/hip_bf16.h>
#include <math.h>

// ---------------- problem constants ----------------
#define N_ROWS 65536
#define H 256
#define DOUT 64
#define NC 4
#define NLAYERS_HIDDEN 3
#define DIN_PE 84
#define KPE 96          // padded K for layer 0 (84 -> 96, zeros)
#define XE_STRIDE 104   // padded LDS row stride for xe
#define BM 64           // rows per block
#define FB_STRIDE 68    // fp32 out-staging row stride

// fragment-ordered weight chunk: one (kstep, nblk) pair = 64 lanes x 8 bf16
#define CHUNK 512
#define WT0_PER_E (3 * 16 * CHUNK)      // 24576
#define WTH_PER_L (8 * 16 * CHUNK)      // 65536
#define WTOUT_PER_E (8 * 4 * CHUNK)     // 16384

using bf16 = __hip_bfloat16;
typedef __bf16 bf16x8 __attribute__((ext_vector_type(8)));
typedef float f32x4 __attribute__((ext_vector_type(4)));

// ---------------- bucket rows by expert ----------------
__global__ void bucket_kernel(const int* __restrict__ layer_id,
                              int* __restrict__ gcnt, int* __restrict__ idx) {
  __shared__ int lcnt[NC];
  __shared__ int lbase[NC];
  const int tid = threadIdx.x;
  if (tid < NC) lcnt[tid] = 0;
  __syncthreads();
  const int i = blockIdx.x * blockDim.x + tid;
  const int e = layer_id[i];
  const int lp = atomicAdd(&lcnt[e], 1);
  __syncthreads();
  if (tid < NC) lbase[tid] = atomicAdd(&gcnt[tid], lcnt[tid]);
  __syncthreads();
  idx[e * N_ROWS + lbase[e] + lp] = i;
}

// ---------------- fp32 -> bf16 fragment-ordered weights ----------------
// element [lane*8 + j] of chunk (kbi,nblk) holds W^T[n][k] with
// n = nblk*16 + (lane&15), k = kbi*32 + (lane>>4)*8 + j.
// This is exactly the MFMA A-fragment layout for A = W^T (row i=n, k-major).
__global__ void prep_weights(const float* __restrict__ W0,
                             const float* __restrict__ Wh,
                             const float* __restrict__ Wout,
                             bf16* __restrict__ wt0, bf16* __restrict__ wth,
                             bf16* __restrict__ wtout) {
  const int n0 = NC * WT0_PER_E;
  const int nh = NC * 3 * WTH_PER_L;
  const int no = NC * WTOUT_PER_E;
  const int total = n0 + nh + no;
  for (int i = blockIdx.x * blockDim.x + threadIdx.x; i < total;
       i += gridDim.x * blockDim.x) {
    if (i < n0) {
      int c = i / WT0_PER_E; int r = i % WT0_PER_E;
      int kbi = r / (16 * CHUNK); int r2 = r % (16 * CHUNK);
      int nblk = r2 / CHUNK; int w = r2 % CHUNK;
      int lane = w / 8, j = w % 8;
      int n = nblk * 16 + (lane & 15);
      int k = kbi * 32 + (lane >> 4) * 8 + j;
      float v = (k < DIN_PE) ? W0[(c * DIN_PE + k) * H + n] : 0.f;
      wt0[i] = __float2bfloat16(v);
    } else if (i < n0 + nh) {
      int u = i - n0;
      int cl = u / WTH_PER_L; int r = u % WTH_PER_L;   // cl = c*3 + l
      int kbi = r / (16 * CHUNK); int r2 = r % (16 * CHUNK);
      int nblk = r2 / CHUNK; int w = r2 % CHUNK;
      int lane = w / 8, j = w % 8;
      int n = nblk * 16 + (lane & 15);
      int k = kbi * 32 + (lane >> 4) * 8 + j;
      wth[u] = __float2bfloat16(Wh[(cl * H + k) * H + n]);
    } else {
      int u = i - n0 - nh;
      int c = u / WTOUT_PER_E; int r = u % WTOUT_PER_E;
      int kbi = r / (4 * CHUNK); int r2 = r % (4 * CHUNK);
      int nblk = r2 / CHUNK; int w = r2 % CHUNK;
      int lane = w / 8, j = w % 8;
      int n = nblk * 16 + (lane & 15);
      int k = kbi * 32 + (lane >> 4) * 8 + j;
      wtout[u] = __float2bfloat16(Wout[(c * H + k) * DOUT + n]);
    }
  }
}

// ---------------- main fused MLP (whole-layer reg-resident weights) --------
// Swapped-operand MFMA (h'^T = W^T h^T) as R8. New: each wave preloads its
// ENTIRE per-layer weight slice (bf16x8 aw[8][4] = 128 VGPR) in one burst;
// K-loops run purely from registers+LDS. Next layer's weights are issued
// right after the last MFMA using the current ones, hiding L2 latency under
// the epilogue+barrier. waves_per_eu(2,2) pins the 256-VGPR budget so the
// allocator cannot chase 4 waves/EU and spill (R3/R4/R6 failure mode).
__global__ __attribute__((amdgpu_flat_work_group_size(256, 256),
                          amdgpu_waves_per_eu(2, 2)))
void mlp_kernel(
    const float* __restrict__ x, const float* __restrict__ in_dim,
    const int* __restrict__ gcnt, const int* __restrict__ idx,
    const bf16* __restrict__ wt0, const float* __restrict__ b0,
    const bf16* __restrict__ wth, const float* __restrict__ bh,
    const float* __restrict__ scal, const bf16* __restrict__ wtout,
    const float* __restrict__ bout, float* __restrict__ out) {
  const int bid = blockIdx.x;
  const int c0 = gcnt[0], c1 = gcnt[1], c2 = gcnt[2], c3 = gcnt[3];
  const int n0 = (c0 + 63) >> 6, n1 = (c1 + 63) >> 6, n2 = (c2 + 63) >> 6,
            n3 = (c3 + 63) >> 6;
  int e, tb, cnt;
  if (bid < n0) { e = 0; tb = bid; cnt = c0; }
  else if (bid < n0 + n1) { e = 1; tb = bid - n0; cnt = c1; }
  else if (bid < n0 + n1 + n2) { e = 2; tb = bid - n0 - n1; cnt = c2; }
  else if (bid < n0 + n1 + n2 + n3) { e = 3; tb = bid - n0 - n1 - n2; cnt = c3; }
  else return;
  const int base = tb * BM;

  const int tid = threadIdx.x;
  const int lane = tid & 63;
  const int wid = tid >> 6;
  const int l15 = lane & 15;
  const int lq = lane >> 4;
  const int wb = wid * 64;  // this wave's n' (hidden-out) base

  // per-wave weight slice for one layer, register-resident
  bf16x8 aw[8][4];

  // ---- issue layer-0 weight loads FIRST (hide under PE sincos) ----
  {
    const bf16* W = wt0 + (size_t)e * WT0_PER_E + lane * 8;
#pragma unroll
    for (int kb = 0; kb < 3; ++kb)
#pragma unroll
      for (int it = 0; it < 4; ++it)
        aw[kb][it] = *(const bf16x8*)(W + (kb * 16 + wid * 4 + it) * CHUNK);
  }

  __shared__ int ridx[BM];
  __shared__ float indim_s[BM];
  // overlays: xe [64][104] bf16 (13312B) -> hs [64 m][256 n] bf16 swizzled
  // (32768B) -> fbuf [64][68] f32 (17408B). Barrier-protected transitions.
  __shared__ __align__(16) char smem[BM * H * 2];
  bf16* xe = (bf16*)smem;
  bf16* hs = (bf16*)smem;
  float* fbuf = (float*)smem;

  if (tid < BM) {
    int p = base + tid;
    int ri = (p < cnt) ? idx[e * N_ROWS + p] : -1;
    ridx[tid] = ri;
    indim_s[tid] = (ri >= 0) ? in_dim[ri] : 1.f;
  }
  __syncthreads();

  // ---- positional encoding: 4 threads per row ----
  {
    const int r = tid >> 2, d = tid & 3;
    const int ri = ridx[r];
    float xd = 0.f, x3 = 1.f;
    if (ri >= 0) { xd = x[ri * 4 + d]; x3 = x[ri * 4 + 3]; }
    float v = (d < 3) ? (xd / x3) : x3;
    if (ri < 0) v = 0.f;
    bf16* row = xe + r * XE_STRIDE;
    row[d] = __float2bfloat16(v);
    float f = 3.14159265358979323846f;
#pragma unroll 1
    for (int q = 0; q < 10; ++q) {
      float sn, cs;
      __sincosf(v * f, &sn, &cs);
      row[4 + q * 8 + d * 2] = __float2bfloat16(sn);
      row[4 + q * 8 + d * 2 + 1] = __float2bfloat16(cs);
      f *= 2.f;
    }
#pragma unroll 1
    for (int c = DIN_PE + d; c < XE_STRIDE; c += 4) row[c] = __float2bfloat16(0.f);
  }
  __syncthreads();

  f32x4 acc[4][4];  // [it = n'-tile][jt = m-tile]

  // ---- layer 0: h1^T = (W0^T)(xe^T), weights already in aw[0..2] ----
  {
    const float* bias = b0 + e * H + wb;
#pragma unroll
    for (int it = 0; it < 4; ++it) {
      f32x4 bv = *(const f32x4*)(bias + it * 16 + lq * 4);
#pragma unroll
      for (int jt = 0; jt < 4; ++jt) acc[it][jt] = bv;
    }
#pragma unroll
    for (int kb = 0; kb < 3; ++kb) {
      bf16x8 bx[4];
#pragma unroll
      for (int jt = 0; jt < 4; ++jt)
        bx[jt] = *(const bf16x8*)(xe + (jt * 16 + l15) * XE_STRIDE + kb * 32 + lq * 8);
#pragma unroll
      for (int it = 0; it < 4; ++it)
#pragma unroll
        for (int jt = 0; jt < 4; ++jt)
          acc[it][jt] = __builtin_amdgcn_mfma_f32_16x16x32_bf16(
              aw[kb][it], bx[jt], acc[it][jt], 0, 0, 0);
    }
    // prefetch hidden layer 0's full weight slice (hides under epilogue)
    {
      const bf16* Wn = wth + (size_t)(e * 3 + 0) * WTH_PER_L + lane * 8;
#pragma unroll
      for (int kb = 0; kb < 8; ++kb)
#pragma unroll
        for (int it = 0; it < 4; ++it)
          aw[kb][it] = *(const bf16x8*)(Wn + (kb * 16 + wid * 4 + it) * CHUNK);
    }
    __syncthreads();  // all waves done reading xe before hs overwrites it
    // epilogue: relu -> b64 write per tile (lane: m=l15 fixed, 4 consec n')
#pragma unroll
    for (int it = 0; it < 4; ++it)
#pragma unroll
      for (int jt = 0; jt < 4; ++jt) {
        int m = jt * 16 + l15;
        int nb = wb + it * 16 + lq * 4;
        int byte = ((m * H + nb) * 2) ^ ((l15 & 7) << 4);
        bf16 neu[4];
#pragma unroll
        for (int r = 0; r < 4; ++r)
          neu[r] = __float2bfloat16(fmaxf(acc[it][jt][r], 0.f));
        *(ushort4*)((char*)hs + byte) = *(ushort4*)neu;
      }
  }
  __syncthreads();

  // ---- hidden residual layers (weights fully reg-resident per layer) ----
#pragma unroll 1
  for (int l = 0; l < NLAYERS_HIDDEN; ++l) {
    const float* bias = bh + (e * 3 + l) * H + wb;
    const float sc = scal[e * 3 + l];
#pragma unroll
    for (int it = 0; it < 4; ++it) {
      f32x4 bv = *(const f32x4*)(bias + it * 16 + lq * 4);
#pragma unroll
      for (int jt = 0; jt < 4; ++jt) acc[it][jt] = bv;
    }
#pragma unroll
    for (int kb = 0; kb < 8; ++kb) {
      bf16x8 bx[4];
#pragma unroll
      for (int jt = 0; jt < 4; ++jt) {
        int m = jt * 16 + l15;
        int byte = ((m * H + kb * 32 + lq * 8) * 2) ^ ((l15 & 7) << 4);
        bx[jt] = *(const bf16x8*)((const char*)hs + byte);
      }
#pragma unroll
      for (int it = 0; it < 4; ++it)
#pragma unroll
        for (int jt = 0; jt < 4; ++jt)
          acc[it][jt] = __builtin_amdgcn_mfma_f32_16x16x32_bf16(
              aw[kb][it], bx[jt], acc[it][jt], 0, 0, 0);
    }
    // prefetch next layer's weights (or wtout) -- last use of aw was above
    if (l < NLAYERS_HIDDEN - 1) {
      const bf16* Wn = wth + (size_t)(e * 3 + l + 1) * WTH_PER_L + lane * 8;
#pragma unroll
      for (int kb = 0; kb < 8; ++kb)
#pragma unroll
        for (int it = 0; it < 4; ++it)
          aw[kb][it] = *(const bf16x8*)(Wn + (kb * 16 + wid * 4 + it) * CHUNK);
    } else {
      const bf16* Wn = wtout + (size_t)e * WTOUT_PER_E + lane * 8;
#pragma unroll
      for (int kb = 0; kb < 8; ++kb)
        aw[kb][0] = *(const bf16x8*)(Wn + (kb * 4 + wid) * CHUNK);
    }
    __syncthreads();  // all waves done READING hs before overwrite
    // epilogue: b64 RMW per tile (residual = same-thread previous write)
#pragma unroll
    for (int it = 0; it < 4; ++it)
#pragma unroll
      for (int jt = 0; jt < 4; ++jt) {
        int m = jt * 16 + l15;
        int nb = wb + it * 16 + lq * 4;
        int byte = ((m * H + nb) * 2) ^ ((l15 & 7) << 4);
        ushort4* p = (ushort4*)((char*)hs + byte);
        bf16 old[4]; *(ushort4*)old = *p;
        bf16 neu[4];
#pragma unroll
        for (int r = 0; r < 4; ++r) {
          float hv = sc * fmaxf(acc[it][jt][r], 0.f) + __bfloat162float(old[r]);
          neu[r] = __float2bfloat16(hv);
        }
        *p = *(ushort4*)neu;
      }
    __syncthreads();
  }

  // ---- output layer: out^T = (Wout^T)(h^T), weights in aw[*][0] ----
  {
    const float* bias = bout + e * DOUT + wid * 16;
    f32x4 facc[4];
    f32x4 bv = *(const f32x4*)(bias + lq * 4);
#pragma unroll
    for (int jt = 0; jt < 4; ++jt) facc[jt] = bv;
#pragma unroll
    for (int kb = 0; kb < 8; ++kb) {
      bf16x8 bx[4];
#pragma unroll
      for (int jt = 0; jt < 4; ++jt) {
        int m = jt * 16 + l15;
        int byte = ((m * H + kb * 32 + lq * 8) * 2) ^ ((l15 & 7) << 4);
        bx[jt] = *(const bf16x8*)((const char*)hs + byte);
      }
#pragma unroll
      for (int jt = 0; jt < 4; ++jt)
        facc[jt] = __builtin_amdgcn_mfma_f32_16x16x32_bf16(
            aw[kb][0], bx[jt], facc[jt], 0, 0, 0);
    }
    __syncthreads();  // hs dead; fbuf overlays it
    // lane holds (m = jt*16+l15, o = wid*16 + lq*4 + r): f32x4 store per jt
#pragma unroll
    for (int jt = 0; jt < 4; ++jt) {
      int m = jt * 16 + l15;
      *(f32x4*)(fbuf + m * FB_STRIDE + wid * 16 + lq * 4) = facc[jt];
    }
  }
  __syncthreads();

  // ---- coalesced scatter: full 256B rows via float4 lanes ----
#pragma unroll 1
  for (int p = 0; p < 4; ++p) {
    int item = p * 256 + tid;
    int row = item >> 4;
    int ch = item & 15;
    int ri = ridx[row];
    if (ri >= 0) {
      f32x4 v = *(const f32x4*)(fbuf + row * FB_STRIDE + ch * 4);
      float inv = indim_s[row];
      v[0] /= inv; v[1] /= inv; v[2] /= inv; v[3] /= inv;
      *(f32x4*)(out + (size_t)ri * DOUT + ch * 4) = v;
    }
  }
}

// ---------------- launch ----------------
extern "C" void kernel_launch(void* const* d_in, const int* in_sizes, int n_in,
                              void* d_out, int out_size, void* d_ws,
                              size_t ws_size, hipStream_t stream) {
  const float* x = (const float*)d_in[0];
  const float* in_dim = (const float*)d_in[1];
  const int* layer_id = (const int*)d_in[2];
  const float* W0 = (const float*)d_in[3];
  const float* b0 = (const float*)d_in[4];
  const float* Wh = (const float*)d_in[5];
  const float* bh = (const float*)d_in[6];
  const float* scal = (const float*)d_in[7];
  const float* Wout = (const float*)d_in[8];
  const float* bout = (const float*)d_in[9];
  float* out = (float*)d_out;

  char* ws = (char*)d_ws;
  int* gcnt = (int*)ws;                                  // 16 B
  int* idx = (int*)(ws + 16);                            // NC*N_ROWS*4 = 1 MB
  bf16* wt0 = (bf16*)(ws + 16 + (size_t)NC * N_ROWS * 4);
  bf16* wth = wt0 + NC * WT0_PER_E;
  bf16* wtout = wth + NC * 3 * WTH_PER_L;

  hipMemsetAsync(gcnt, 0, NC * sizeof(int), stream);
  bucket_kernel<<<N_ROWS / 256, 256, 0, stream>>>(layer_id, gcnt, idx);
  prep_weights<<<512, 256, 0, stream>>>(W0, Wh, Wout, wt0, wth, wtout);
  // compact grid: exactly enough blocks to cover all experts (+NC-1 rounding)
  mlp_kernel<<<N_ROWS / BM + NC - 1, 256, 0, stream>>>(
      x, in_dim, gcnt, idx, wt0, b0, wth, bh, scal, wtout, bout, out);
}

// Round 11
// 139.125 us; speedup vs baseline: 1.1558x; 1.1558x over previous
//
#include <hip/hip_runtime.h>
#include <hip/hip_bf16.h>
#include <math.h>

// ---------------- problem constants ----------------
#define N_ROWS 65536
#define H 256
#define DOUT 64
#define NC 4
#define NLAYERS_HIDDEN 3
#define DIN_PE 84
#define XE_STRIDE 104   // padded LDS row stride for xe
#define BM 64           // rows per block
#define FB_STRIDE 68    // fp32 out-staging row stride

// fragment-ordered weight chunk: one (kstep, nblk) pair = 64 lanes x 8 bf16.
// All region sizes are powers of two so setup indexing is pure bit-ops:
// wt0 padded to 4 kstep-groups (only 3 real; group 3 is zeros).
#define CHUNK 512
#define WT0_PER_E 32768                 // 4*16*CHUNK (pow2, kbi=3 zero-pad)
#define WTH_PER_L 65536                 // 8*16*CHUNK
#define WTOUT_PER_E 16384               // 8*4*CHUNK
#define N_WT0 (NC * WT0_PER_E)          // 131072
#define N_WTH (NC * 3 * WTH_PER_L)      // 786432
#define N_WTOUT (NC * WTOUT_PER_E)      // 65536
#define N_PREP (N_WT0 + N_WTH + N_WTOUT)  // 983040

using bf16 = __hip_bfloat16;
typedef __bf16 bf16x8 __attribute__((ext_vector_type(8)));
typedef float f32x4 __attribute__((ext_vector_type(4)));

// ---------------- fused setup: bucket rows + fp32->bf16 weight reorder ----
// blocks [0,256): bucket 65536 rows by expert (LDS histogram + 1 global
// atomic per expert per block). blocks [256,4096): one element per thread of
// fragment-ordered weight conversion -- ALL indexing is shifts/masks (pow2
// regions), replacing R8's div/mod chains that made prep_weights slow.
// element [lane*8+j] of chunk (kbi,nblk) holds W^T[n][k], n=nblk*16+(lane&15),
// k=kbi*32+(lane>>4)*8+j  == the MFMA A-fragment layout for A = W^T.
__global__ void setup_kernel(const int* __restrict__ layer_id,
                             int* __restrict__ gcnt, int* __restrict__ idx,
                             const float* __restrict__ W0,
                             const float* __restrict__ Wh,
                             const float* __restrict__ Wout,
                             bf16* __restrict__ wt0, bf16* __restrict__ wth,
                             bf16* __restrict__ wtout) {
  const int bid = blockIdx.x;
  const int tid = threadIdx.x;
  if (bid < 256) {
    __shared__ int lcnt[NC];
    __shared__ int lbase[NC];
    if (tid < NC) lcnt[tid] = 0;
    __syncthreads();
    const int i = bid * 256 + tid;
    const int e = layer_id[i];
    const int lp = atomicAdd(&lcnt[e], 1);
    __syncthreads();
    if (tid < NC) lbase[tid] = atomicAdd(&gcnt[tid], lcnt[tid]);
    __syncthreads();
    idx[e * N_ROWS + lbase[e] + lp] = i;
    return;
  }
  const int i = (bid - 256) * 256 + tid;
  if (i < N_WT0) {
    int c = i >> 15, r = i & (WT0_PER_E - 1);
    int kbi = r >> 13, r2 = r & 8191;
    int nblk = r2 >> 9, w = r2 & 511;
    int lane = w >> 3, j = w & 7;
    int n = (nblk << 4) | (lane & 15);
    int k = (kbi << 5) | ((lane >> 4) << 3) | j;
    wt0[i] = __float2bfloat16(k < DIN_PE ? W0[(c * DIN_PE + k) * H + n] : 0.f);
  } else if (i < N_WT0 + N_WTH) {
    int u = i - N_WT0;
    int cl = u >> 16, r = u & 65535;        // cl = c*3 + l
    int kbi = r >> 13;
    int nblk = (r >> 9) & 15, w = r & 511;
    int lane = w >> 3, j = w & 7;
    int n = (nblk << 4) | (lane & 15);
    int k = (kbi << 5) | ((lane >> 4) << 3) | j;
    wth[u] = __float2bfloat16(Wh[(cl << 16) | (k << 8) | n]);
  } else if (i < N_PREP) {
    int u = i - N_WT0 - N_WTH;
    int c = u >> 14, r = u & 16383;
    int kbi = r >> 11;
    int nblk = (r >> 9) & 3, w = r & 511;
    int lane = w >> 3, j = w & 7;
    int n = (nblk << 4) | (lane & 15);
    int k = (kbi << 5) | ((lane >> 4) << 3) | j;
    wtout[u] = __float2bfloat16(Wout[(c << 14) | (k << 6) | n]);
  }
}

// ---------------- main fused MLP (R8 structure: proven 61.5us) ------------
// Swapped-operand MFMA: h'^T = (W^T)(h^T). A-frag = fragment-ordered weight
// (coalesced 1KB global loads, ping-pong distance-1 prefetch), B-frag =
// activation hs[m][n] (swizzled b128 LDS read). D-layout: lane holds m=l15
// fixed, 4 consecutive n' -> epilogue is one b64 RMW per tile. Compact 1D
// grid: block bid -> (expert, tile) via ceil-div scan of gcnt. launch_bounds
// min-waves=3 keeps VGPR ~68: NO SPILLS (>~130 VGPR configs spilled in
// R3/R4/R6/R10 -- FETCH/WRITE inflation is the tripwire).
__global__ __launch_bounds__(256, 3) void mlp_kernel(
    const float* __restrict__ x, const float* __restrict__ in_dim,
    const int* __restrict__ gcnt, const int* __restrict__ idx,
    const bf16* __restrict__ wt0, const float* __restrict__ b0,
    const bf16* __restrict__ wth, const float* __restrict__ bh,
    const float* __restrict__ scal, const bf16* __restrict__ wtout,
    const float* __restrict__ bout, float* __restrict__ out) {
  const int bid = blockIdx.x;
  const int c0 = gcnt[0], c1 = gcnt[1], c2 = gcnt[2], c3 = gcnt[3];
  const int n0 = (c0 + 63) >> 6, n1 = (c1 + 63) >> 6, n2 = (c2 + 63) >> 6,
            n3 = (c3 + 63) >> 6;
  int e, tb, cnt;
  if (bid < n0) { e = 0; tb = bid; cnt = c0; }
  else if (bid < n0 + n1) { e = 1; tb = bid - n0; cnt = c1; }
  else if (bid < n0 + n1 + n2) { e = 2; tb = bid - n0 - n1; cnt = c2; }
  else if (bid < n0 + n1 + n2 + n3) { e = 3; tb = bid - n0 - n1 - n2; cnt = c3; }
  else return;
  const int base = tb * BM;

  __shared__ int ridx[BM];
  __shared__ float indim_s[BM];
  // overlays: xe [64][104] bf16 (13312B) -> hs [64 m][256 n] bf16 swizzled
  // (32768B) -> fbuf [64][68] f32 (17408B). Barrier-protected transitions.
  __shared__ __align__(16) char smem[BM * H * 2];
  bf16* xe = (bf16*)smem;
  bf16* hs = (bf16*)smem;
  float* fbuf = (float*)smem;

  const int tid = threadIdx.x;
  if (tid < BM) {
    int p = base + tid;
    int ri = (p < cnt) ? idx[e * N_ROWS + p] : -1;
    ridx[tid] = ri;
    indim_s[tid] = (ri >= 0) ? in_dim[ri] : 1.f;
  }
  __syncthreads();

  // ---- positional encoding: 4 threads per row ----
  {
    const int r = tid >> 2, d = tid & 3;
    const int ri = ridx[r];
    float xd = 0.f, x3 = 1.f;
    if (ri >= 0) { xd = x[ri * 4 + d]; x3 = x[ri * 4 + 3]; }
    float v = (d < 3) ? (xd / x3) : x3;
    if (ri < 0) v = 0.f;
    bf16* row = xe + r * XE_STRIDE;
    row[d] = __float2bfloat16(v);
    float f = 3.14159265358979323846f;
#pragma unroll 1
    for (int q = 0; q < 10; ++q) {
      float sn, cs;
      __sincosf(v * f, &sn, &cs);
      row[4 + q * 8 + d * 2] = __float2bfloat16(sn);
      row[4 + q * 8 + d * 2 + 1] = __float2bfloat16(cs);
      f *= 2.f;
    }
#pragma unroll 1
    for (int c = DIN_PE + d; c < XE_STRIDE; c += 4) row[c] = __float2bfloat16(0.f);
  }
  __syncthreads();

  const int lane = tid & 63;
  const int wid = tid >> 6;
  const int l15 = lane & 15;
  const int lq = lane >> 4;
  const int wb = wid * 64;  // this wave's n' (hidden-out) base

  f32x4 acc[4][4];  // [it = n'-tile][jt = m-tile]

  // ---- layer 0: h1^T = (W0^T)(xe^T), B-frag from row-major xe ----
  {
    const bf16* W = wt0 + (size_t)e * WT0_PER_E + lane * 8;
    const float* bias = b0 + e * H + wb;
#pragma unroll
    for (int it = 0; it < 4; ++it) {
      f32x4 bv = *(const f32x4*)(bias + it * 16 + lq * 4);
#pragma unroll
      for (int jt = 0; jt < 4; ++jt) acc[it][jt] = bv;
    }
#pragma unroll 1
    for (int kb = 0; kb < 3; ++kb) {  // kstep index (K = 3*32)
      bf16x8 aw[4], bx[4];
#pragma unroll
      for (int it = 0; it < 4; ++it)
        aw[it] = *(const bf16x8*)(W + (kb * 16 + wid * 4 + it) * CHUNK);
#pragma unroll
      for (int jt = 0; jt < 4; ++jt)
        bx[jt] = *(const bf16x8*)(xe + (jt * 16 + l15) * XE_STRIDE + kb * 32 + lq * 8);
#pragma unroll
      for (int it = 0; it < 4; ++it)
#pragma unroll
        for (int jt = 0; jt < 4; ++jt)
          acc[it][jt] = __builtin_amdgcn_mfma_f32_16x16x32_bf16(
              aw[it], bx[jt], acc[it][jt], 0, 0, 0);
    }
    __syncthreads();  // all waves done reading xe before hs overwrites it
    // epilogue: relu -> b64 write per tile (lane: m=l15 fixed, 4 consec n')
#pragma unroll
    for (int it = 0; it < 4; ++it)
#pragma unroll
      for (int jt = 0; jt < 4; ++jt) {
        int m = jt * 16 + l15;
        int nb = wb + it * 16 + lq * 4;
        int byte = ((m * H + nb) * 2) ^ ((l15 & 7) << 4);
        bf16 neu[4];
#pragma unroll
        for (int r = 0; r < 4; ++r)
          neu[r] = __float2bfloat16(fmaxf(acc[it][jt][r], 0.f));
        *(ushort4*)((char*)hs + byte) = *(ushort4*)neu;
      }
  }
  __syncthreads();

  // ---- hidden residual layers (rolled; ping-pong weight prefetch) ----
#pragma unroll 1
  for (int l = 0; l < NLAYERS_HIDDEN; ++l) {
    const bf16* W = wth + (size_t)(e * 3 + l) * WTH_PER_L + lane * 8;
    const float* bias = bh + (e * 3 + l) * H + wb;
    const float sc = scal[e * 3 + l];
#pragma unroll
    for (int it = 0; it < 4; ++it) {
      f32x4 bv = *(const f32x4*)(bias + it * 16 + lq * 4);
#pragma unroll
      for (int jt = 0; jt < 4; ++jt) acc[it][jt] = bv;
    }
    bf16x8 aw0[4], aw1[4];
#pragma unroll
    for (int it = 0; it < 4; ++it)
      aw0[it] = *(const bf16x8*)(W + (wid * 4 + it) * CHUNK);
#pragma unroll 1
    for (int kb = 0; kb < 8; kb += 2) {
      // half A: prefetch aw1 <- kb+1, compute with aw0 (kb)
#pragma unroll
      for (int it = 0; it < 4; ++it)
        aw1[it] = *(const bf16x8*)(W + ((kb + 1) * 16 + wid * 4 + it) * CHUNK);
      {
        bf16x8 bx[4];
#pragma unroll
        for (int jt = 0; jt < 4; ++jt) {
          int m = jt * 16 + l15;
          int byte = ((m * H + kb * 32 + lq * 8) * 2) ^ ((l15 & 7) << 4);
          bx[jt] = *(const bf16x8*)((const char*)hs + byte);
        }
#pragma unroll
        for (int it = 0; it < 4; ++it)
#pragma unroll
          for (int jt = 0; jt < 4; ++jt)
            acc[it][jt] = __builtin_amdgcn_mfma_f32_16x16x32_bf16(
                aw0[it], bx[jt], acc[it][jt], 0, 0, 0);
      }
      // half B: prefetch aw0 <- kb+2 (wraps harmlessly), compute aw1
      {
        int kn = (kb + 2) & 7;
#pragma unroll
        for (int it = 0; it < 4; ++it)
          aw0[it] = *(const bf16x8*)(W + (kn * 16 + wid * 4 + it) * CHUNK);
        bf16x8 bx[4];
#pragma unroll
        for (int jt = 0; jt < 4; ++jt) {
          int m = jt * 16 + l15;
          int byte = ((m * H + (kb + 1) * 32 + lq * 8) * 2) ^ ((l15 & 7) << 4);
          bx[jt] = *(const bf16x8*)((const char*)hs + byte);
        }
#pragma unroll
        for (int it = 0; it < 4; ++it)
#pragma unroll
          for (int jt = 0; jt < 4; ++jt)
            acc[it][jt] = __builtin_amdgcn_mfma_f32_16x16x32_bf16(
                aw1[it], bx[jt], acc[it][jt], 0, 0, 0);
      }
    }
    __syncthreads();  // all waves done READING hs before overwrite
    // epilogue: b64 RMW per tile (residual = same-thread previous write)
#pragma unroll
    for (int it = 0; it < 4; ++it)
#pragma unroll
      for (int jt = 0; jt < 4; ++jt) {
        int m = jt * 16 + l15;
        int nb = wb + it * 16 + lq * 4;
        int byte = ((m * H + nb) * 2) ^ ((l15 & 7) << 4);
        ushort4* p = (ushort4*)((char*)hs + byte);
        bf16 old[4]; *(ushort4*)old = *p;
        bf16 neu[4];
#pragma unroll
        for (int r = 0; r < 4; ++r) {
          float hv = sc * fmaxf(acc[it][jt][r], 0.f) + __bfloat162float(old[r]);
          neu[r] = __float2bfloat16(hv);
        }
        *p = *(ushort4*)neu;
      }
    __syncthreads();
  }

  // ---- output layer: out^T = (Wout^T)(h^T) -> fbuf[m][o] fp32 ----
  {
    const bf16* W = wtout + (size_t)e * WTOUT_PER_E + lane * 8;
    const float* bias = bout + e * DOUT + wid * 16;
    f32x4 facc[4];
    f32x4 bv = *(const f32x4*)(bias + lq * 4);
#pragma unroll
    for (int jt = 0; jt < 4; ++jt) facc[jt] = bv;
    bf16x8 aw0, aw1;
    aw0 = *(const bf16x8*)(W + wid * CHUNK);
#pragma unroll 1
    for (int kb = 0; kb < 8; kb += 2) {
      aw1 = *(const bf16x8*)(W + ((kb + 1) * 4 + wid) * CHUNK);
      {
        bf16x8 bx[4];
#pragma unroll
        for (int jt = 0; jt < 4; ++jt) {
          int m = jt * 16 + l15;
          int byte = ((m * H + kb * 32 + lq * 8) * 2) ^ ((l15 & 7) << 4);
          bx[jt] = *(const bf16x8*)((const char*)hs + byte);
        }
#pragma unroll
        for (int jt = 0; jt < 4; ++jt)
          facc[jt] = __builtin_amdgcn_mfma_f32_16x16x32_bf16(aw0, bx[jt], facc[jt], 0, 0, 0);
      }
      {
        int kn = (kb + 2) & 7;
        aw0 = *(const bf16x8*)(W + (kn * 4 + wid) * CHUNK);
        bf16x8 bx[4];
#pragma unroll
        for (int jt = 0; jt < 4; ++jt) {
          int m = jt * 16 + l15;
          int byte = ((m * H + (kb + 1) * 32 + lq * 8) * 2) ^ ((l15 & 7) << 4);
          bx[jt] = *(const bf16x8*)((const char*)hs + byte);
        }
#pragma unroll
        for (int jt = 0; jt < 4; ++jt)
          facc[jt] = __builtin_amdgcn_mfma_f32_16x16x32_bf16(aw1, bx[jt], facc[jt], 0, 0, 0);
      }
    }
    __syncthreads();  // hs dead; fbuf overlays it
    // lane holds (m = jt*16+l15, o = wid*16 + lq*4 + r): f32x4 store per jt
#pragma unroll
    for (int jt = 0; jt < 4; ++jt) {
      int m = jt * 16 + l15;
      *(f32x4*)(fbuf + m * FB_STRIDE + wid * 16 + lq * 4) = facc[jt];
    }
  }
  __syncthreads();

  // ---- coalesced scatter: full 256B rows via float4 lanes ----
#pragma unroll 1
  for (int p = 0; p < 4; ++p) {
    int item = p * 256 + tid;
    int row = item >> 4;
    int ch = item & 15;
    int ri = ridx[row];
    if (ri >= 0) {
      f32x4 v = *(const f32x4*)(fbuf + row * FB_STRIDE + ch * 4);
      float inv = indim_s[row];
      v[0] /= inv; v[1] /= inv; v[2] /= inv; v[3] /= inv;
      *(f32x4*)(out + (size_t)ri * DOUT + ch * 4) = v;
    }
  }
}

// ---------------- launch ----------------
extern "C" void kernel_launch(void* const* d_in, const int* in_sizes, int n_in,
                              void* d_out, int out_size, void* d_ws,
                              size_t ws_size, hipStream_t stream) {
  const float* x = (const float*)d_in[0];
  const float* in_dim = (const float*)d_in[1];
  const int* layer_id = (const int*)d_in[2];
  const float* W0 = (const float*)d_in[3];
  const float* b0 = (const float*)d_in[4];
  const float* Wh = (const float*)d_in[5];
  const float* bh = (const float*)d_in[6];
  const float* scal = (const float*)d_in[7];
  const float* Wout = (const float*)d_in[8];
  const float* bout = (const float*)d_in[9];
  float* out = (float*)d_out;

  char* ws = (char*)d_ws;
  int* gcnt = (int*)ws;                                  // 16 B
  int* idx = (int*)(ws + 16);                            // NC*N_ROWS*4 = 1 MB
  bf16* wt0 = (bf16*)(ws + 16 + (size_t)NC * N_ROWS * 4);
  bf16* wth = wt0 + N_WT0;
  bf16* wtout = wth + N_WTH;

  hipMemsetAsync(gcnt, 0, NC * sizeof(int), stream);
  // fused bucket (256 blocks) + weight reorder (3840 blocks)
  setup_kernel<<<256 + N_PREP / 256, 256, 0, stream>>>(
      layer_id, gcnt, idx, W0, Wh, Wout, wt0, wth, wtout);
  // compact grid: exactly enough blocks to cover all experts (+NC-1 rounding)
  mlp_kernel<<<N_ROWS / BM + NC - 1, 256, 0, stream>>>(
      x, in_dim, gcnt, idx, wt0, b0, wth, bh, scal, wtout, bout, out);
}